// Round 1
// baseline (38.673 us; speedup 1.0000x reference)
//
#include <hip/hip_runtime.h>
#include <stdint.h>

#define NQ 4
#define OUTHW 511
#define IMGW 512
#define NOPS_MAX 64

struct OpsPack {
    int n;
    int kind[NOPS_MAX];   // 0=RX 1=RY 2=RZ 3=CNOT
    int wa[NOPS_MAX];     // wire (rot) or control (CNOT)
    int wb[NOPS_MAX];     // target (CNOT)
    int widx[NOPS_MAX];   // flat weight index l*4+i for rotations
};

// ---------- host-side MT19937, numpy RandomState-compatible ----------
namespace {
struct MT19937 {
    uint32_t mt[624]; int mti;
    explicit MT19937(uint32_t s) {
        mt[0] = s;
        for (int i = 1; i < 624; ++i)
            mt[i] = 1812433253u * (mt[i - 1] ^ (mt[i - 1] >> 30)) + (uint32_t)i;
        mti = 624;
    }
    uint32_t next32() {
        if (mti >= 624) {
            for (int i = 0; i < 624; ++i) {
                uint32_t y = (mt[i] & 0x80000000u) | (mt[(i + 1) % 624] & 0x7fffffffu);
                mt[i] = mt[(i + 397) % 624] ^ (y >> 1) ^ ((y & 1u) ? 0x9908b0dfu : 0u);
            }
            mti = 0;
        }
        uint32_t y = mt[mti++];
        y ^= y >> 11;
        y ^= (y << 7) & 0x9d2c5680u;
        y ^= (y << 15) & 0xefc60000u;
        y ^= y >> 18;
        return y;
    }
    double rand_double() {  // random_sample(): 2 draws
        uint32_t a = next32() >> 5, b = next32() >> 6;
        return (a * 67108864.0 + b) / 9007199254740992.0;
    }
    // numpy random_interval / legacy masked randint over [0, mx], 32-bit path
    uint32_t interval(uint32_t mx) {
        if (mx == 0) return 0;
        uint32_t mask = mx;
        mask |= mask >> 1; mask |= mask >> 2; mask |= mask >> 4;
        mask |= mask >> 8; mask |= mask >> 16;
        uint32_t v;
        while ((v = (next32() & mask)) > mx) {}
        return v;
    }
};

OpsPack build_ops() {
    MT19937 mt(42u);
    OpsPack P; P.n = 0;
    for (int l = 0; l < 2; ++l) {
        int i = 0;
        while (i < 4 && P.n < NOPS_MAX) {
            if (mt.rand_double() > 0.3) {
                int g = (int)mt.interval(2);  // randint(3): mask=3, reject ==3
                int w = (int)mt.interval(3);  // randint(4): mask=3, never rejects
                P.kind[P.n] = g; P.wa[P.n] = w; P.wb[P.n] = 0; P.widx[P.n] = l * 4 + i;
                ++P.n; ++i;
            } else {
                // choice(4, size=2, replace=False) == permutation(4)[:2]
                int arr[4] = {0, 1, 2, 3};
                for (int ii = 3; ii >= 1; --ii) {
                    int j = (int)mt.interval((uint32_t)ii);
                    int t = arr[ii]; arr[ii] = arr[j]; arr[j] = t;
                }
                P.kind[P.n] = 3; P.wa[P.n] = arr[0]; P.wb[P.n] = arr[1]; P.widx[P.n] = -1;
                ++P.n;
            }
        }
    }
    return P;
}
}  // namespace

// 4 outputs x 81 monomial coefficients over {1, cos(pi x_k), sin(pi x_k)}^4
__device__ float g_W[4 * 81];

// One block. Builds U (16x16) columns in LDS, then the coefficient table.
__global__ void build_table(const float* __restrict__ wts, OpsPack ops) {
    __shared__ float Ur[256];  // [b*16+n] = Re U[n][b]  (b = input basis col)
    __shared__ float Ui[256];
    const int tid = threadIdx.x;
    for (int e = tid; e < 256; e += blockDim.x) {
        Ur[e] = ((e >> 4) == (e & 15)) ? 1.f : 0.f;
        Ui[e] = 0.f;
    }
    __syncthreads();
    for (int o = 0; o < ops.n; ++o) {
        const int kind = ops.kind[o];
        if (kind == 3) {  // CNOT(control=wa, target=wb)
            const int pc = 3 - ops.wa[o], pt = 3 - ops.wb[o];
            if (tid < 64) {
                int b = tid >> 2, q = tid & 3;
                int rem[2]; int ri = 0;
                for (int p = 0; p < 4; ++p) if (p != pc && p != pt) rem[ri++] = p;
                int n  = (1 << pc) | ((q & 1) ? (1 << rem[0]) : 0)
                                   | (((q >> 1) & 1) ? (1 << rem[1]) : 0);
                int n2 = n | (1 << pt);
                float tr = Ur[b * 16 + n]; Ur[b * 16 + n] = Ur[b * 16 + n2]; Ur[b * 16 + n2] = tr;
                float ti = Ui[b * 16 + n]; Ui[b * 16 + n] = Ui[b * 16 + n2]; Ui[b * 16 + n2] = ti;
            }
        } else {  // rotation on wire wa with angle wts[widx]
            const float th = wts[ops.widx[o]];
            const float ch = cosf(0.5f * th), sh = sinf(0.5f * th);
            const int p = 3 - ops.wa[o];
            if (tid < 128) {
                int b = tid >> 3, q = tid & 7;
                int low = q & ((1 << p) - 1);
                int high = (q >> p) << (p + 1);
                int n0 = high | low, n1 = n0 | (1 << p);
                float a0r = Ur[b * 16 + n0], a0i = Ui[b * 16 + n0];
                float a1r = Ur[b * 16 + n1], a1i = Ui[b * 16 + n1];
                float b0r, b0i, b1r, b1i;
                if (kind == 0) {        // RX: [[c,-is],[-is,c]]
                    b0r = ch * a0r + sh * a1i;  b0i = ch * a0i - sh * a1r;
                    b1r = sh * a0i + ch * a1r;  b1i = -sh * a0r + ch * a1i;
                } else if (kind == 1) { // RY: [[c,-s],[s,c]]
                    b0r = ch * a0r - sh * a1r;  b0i = ch * a0i - sh * a1i;
                    b1r = sh * a0r + ch * a1r;  b1i = sh * a0i + ch * a1i;
                } else {                // RZ: diag(e^{-i th/2}, e^{+i th/2})
                    b0r = ch * a0r + sh * a0i;  b0i = ch * a0i - sh * a0r;
                    b1r = ch * a1r - sh * a1i;  b1i = ch * a1i + sh * a1r;
                }
                Ur[b * 16 + n0] = b0r; Ui[b * 16 + n0] = b0i;
                Ur[b * 16 + n1] = b1r; Ui[b * 16 + n1] = b1i;
            }
        }
        __syncthreads();
    }
    // W_j[t] = (1/16) sum_n z_j(n) sum_b sgn(b&zmask) *
    //          (Ur[n,b]Ur[n,b^xmask] + Ui[n,b]Ui[n,b^xmask])
    if (tid < 324) {
        const int j = tid / 81, t = tid % 81;
        const int d3 = t % 3, d2 = (t / 3) % 3, d1 = (t / 9) % 3, d0 = t / 27;
        const int dd[4] = {d0, d1, d2, d3};
        int zmask = 0, xmask = 0;
        for (int k = 0; k < 4; ++k) {
            int p = 3 - k;
            if (dd[k] == 1) zmask |= 1 << p;
            else if (dd[k] == 2) xmask |= 1 << p;
        }
        float acc = 0.f;
        for (int n = 0; n < 16; ++n) {
            float zj = ((n >> (3 - j)) & 1) ? -1.f : 1.f;
            float s = 0.f;
            for (int b2 = 0; b2 < 16; ++b2) {
                int bx = b2 ^ xmask;
                float sgn = (__popc(b2 & zmask) & 1) ? -1.f : 1.f;
                s += sgn * (Ur[b2 * 16 + n] * Ur[bx * 16 + n] +
                            Ui[b2 * 16 + n] * Ui[bx * 16 + n]);
            }
            acc += zj * s;
        }
        g_W[tid] = acc * 0.0625f;
    }
}

// One thread per output pixel (i,j): 3 channels x 2x2 patch -> 4 outputs.
__global__ void __launch_bounds__(256) quanv_kernel(const float* __restrict__ x,
                                                    float* __restrict__ out) {
    const int j = blockIdx.x * blockDim.x + threadIdx.x;
    const int i = blockIdx.y;
    if (j >= OUTHW) return;

    float mon[81];
#pragma unroll
    for (int t = 0; t < 81; ++t) mon[t] = 0.f;

#pragma unroll
    for (int c = 0; c < 3; ++c) {
        const float* xc = x + c * (IMGW * IMGW);
        const float p00 = xc[i * IMGW + j];
        const float p01 = xc[i * IMGW + j + 1];
        const float p10 = xc[(i + 1) * IMGW + j];
        const float p11 = xc[(i + 1) * IMGW + j + 1];
        float s0, c0, s1, c1, s2, c2, s3, c3;
        sincospif(p00, &s0, &c0);
        sincospif(p01, &s1, &c1);
        sincospif(p10, &s2, &c2);
        sincospif(p11, &s3, &c3);
        const float v0[3] = {1.f, c0, s0};
        const float v1[3] = {1.f, c1, s1};
        const float v2[3] = {1.f, c2, s2};
        const float v3[3] = {1.f, c3, s3};
        float m01[9], m23[9];
#pragma unroll
        for (int a = 0; a < 3; ++a)
#pragma unroll
            for (int b = 0; b < 3; ++b) {
                m01[a * 3 + b] = v0[a] * v1[b];
                m23[a * 3 + b] = v2[a] * v3[b];
            }
#pragma unroll
        for (int a = 0; a < 9; ++a)
#pragma unroll
            for (int b = 0; b < 9; ++b)
                mon[a * 9 + b] = fmaf(m01[a], m23[b], mon[a * 9 + b]);
    }

    float acc0 = 0.f, acc1 = 0.f, acc2 = 0.f, acc3 = 0.f;
#pragma unroll
    for (int t = 0; t < 81; ++t) {
        const float m = mon[t];
        acc0 = fmaf(g_W[t], m, acc0);
        acc1 = fmaf(g_W[81 + t], m, acc1);
        acc2 = fmaf(g_W[162 + t], m, acc2);
        acc3 = fmaf(g_W[243 + t], m, acc3);
    }
    float4 o = make_float4(acc0, acc1, acc2, acc3);
    *reinterpret_cast<float4*>(out + (size_t)(i * OUTHW + j) * 4) = o;
}

extern "C" void kernel_launch(void* const* d_in, const int* in_sizes, int n_in,
                              void* d_out, int out_size, void* d_ws, size_t ws_size,
                              hipStream_t stream) {
    const float* x   = (const float*)d_in[0];   // [1,3,512,512] f32
    const float* wts = (const float*)d_in[1];   // [2,4] f32
    float* out = (float*)d_out;                 // [1,4,511,511] f32 (flat == [i,j,k])

    OpsPack ops = build_ops();  // deterministic host-side MT19937(42) replication

    hipLaunchKernelGGL(build_table, dim3(1), dim3(512), 0, stream, wts, ops);

    dim3 grid((OUTHW + 255) / 256, OUTHW);
    hipLaunchKernelGGL(quanv_kernel, grid, dim3(256), 0, stream, x, out);
}

// Round 2
// 32.325 us; speedup vs baseline: 1.1964x; 1.1964x over previous
//
#include <hip/hip_runtime.h>
#include <stdint.h>

#define NQ 4
#define OUTHW 511
#define IMGW 512
#define NOPS_MAX 64

struct OpsPack {
    int n;
    int kind[NOPS_MAX];   // 0=RX 1=RY 2=RZ 3=CNOT
    int wa[NOPS_MAX];     // wire (rot) or control (CNOT)
    int wb[NOPS_MAX];     // target (CNOT)
    int widx[NOPS_MAX];   // flat weight index l*4+i for rotations
};

// ---------- host-side MT19937, numpy RandomState-compatible ----------
namespace {
struct MT19937 {
    uint32_t mt[624]; int mti;
    explicit MT19937(uint32_t s) {
        mt[0] = s;
        for (int i = 1; i < 624; ++i)
            mt[i] = 1812433253u * (mt[i - 1] ^ (mt[i - 1] >> 30)) + (uint32_t)i;
        mti = 624;
    }
    uint32_t next32() {
        if (mti >= 624) {
            for (int i = 0; i < 624; ++i) {
                uint32_t y = (mt[i] & 0x80000000u) | (mt[(i + 1) % 624] & 0x7fffffffu);
                mt[i] = mt[(i + 397) % 624] ^ (y >> 1) ^ ((y & 1u) ? 0x9908b0dfu : 0u);
            }
            mti = 0;
        }
        uint32_t y = mt[mti++];
        y ^= y >> 11;
        y ^= (y << 7) & 0x9d2c5680u;
        y ^= (y << 15) & 0xefc60000u;
        y ^= y >> 18;
        return y;
    }
    double rand_double() {  // random_sample(): 2 draws
        uint32_t a = next32() >> 5, b = next32() >> 6;
        return (a * 67108864.0 + b) / 9007199254740992.0;
    }
    // numpy random_interval / legacy masked randint over [0, mx], 32-bit path
    uint32_t interval(uint32_t mx) {
        if (mx == 0) return 0;
        uint32_t mask = mx;
        mask |= mask >> 1; mask |= mask >> 2; mask |= mask >> 4;
        mask |= mask >> 8; mask |= mask >> 16;
        uint32_t v;
        while ((v = (next32() & mask)) > mx) {}
        return v;
    }
};

OpsPack build_ops() {
    MT19937 mt(42u);
    OpsPack P; P.n = 0;
    for (int l = 0; l < 2; ++l) {
        int i = 0;
        while (i < 4 && P.n < NOPS_MAX) {
            if (mt.rand_double() > 0.3) {
                int g = (int)mt.interval(2);  // randint(3)
                int w = (int)mt.interval(3);  // randint(4)
                P.kind[P.n] = g; P.wa[P.n] = w; P.wb[P.n] = 0; P.widx[P.n] = l * 4 + i;
                ++P.n; ++i;
            } else {
                // choice(4, size=2, replace=False) == permutation(4)[:2]
                int arr[4] = {0, 1, 2, 3};
                for (int ii = 3; ii >= 1; --ii) {
                    int j = (int)mt.interval((uint32_t)ii);
                    int t = arr[ii]; arr[ii] = arr[j]; arr[j] = t;
                }
                P.kind[P.n] = 3; P.wa[P.n] = arr[0]; P.wb[P.n] = arr[1]; P.widx[P.n] = -1;
                ++P.n;
            }
        }
    }
    return P;
}
}  // namespace

// 4 outputs x 81 monomial coefficients over {1, cos(pi x_k), sin(pi x_k)}^4
__device__ float g_W[4 * 81];

// One block. Builds U (16x16) columns in LDS, then the coefficient table.
__global__ void __launch_bounds__(512) build_table(const float* __restrict__ wts, OpsPack ops) {
    __shared__ float Ur[256];  // [b*16+n] = Re U[n][b]  (b = input basis col)
    __shared__ float Ui[256];
    __shared__ float S[81 * 16];  // partial sums over b, per (t, n)
    const int tid = threadIdx.x;
    for (int e = tid; e < 256; e += blockDim.x) {
        Ur[e] = ((e >> 4) == (e & 15)) ? 1.f : 0.f;
        Ui[e] = 0.f;
    }
    __syncthreads();
    for (int o = 0; o < ops.n; ++o) {
        const int kind = ops.kind[o];
        if (kind == 3) {  // CNOT(control=wa, target=wb)
            const int pc = 3 - ops.wa[o], pt = 3 - ops.wb[o];
            if (tid < 64) {
                int b = tid >> 2, q = tid & 3;
                int rem[2]; int ri = 0;
                for (int p = 0; p < 4; ++p) if (p != pc && p != pt) rem[ri++] = p;
                int n  = (1 << pc) | ((q & 1) ? (1 << rem[0]) : 0)
                                   | (((q >> 1) & 1) ? (1 << rem[1]) : 0);
                int n2 = n | (1 << pt);
                float tr = Ur[b * 16 + n]; Ur[b * 16 + n] = Ur[b * 16 + n2]; Ur[b * 16 + n2] = tr;
                float ti = Ui[b * 16 + n]; Ui[b * 16 + n] = Ui[b * 16 + n2]; Ui[b * 16 + n2] = ti;
            }
        } else {  // rotation on wire wa with angle wts[widx]
            const float th = wts[ops.widx[o]];
            const float ch = cosf(0.5f * th), sh = sinf(0.5f * th);
            const int p = 3 - ops.wa[o];
            if (tid < 128) {
                int b = tid >> 3, q = tid & 7;
                int low = q & ((1 << p) - 1);
                int high = (q >> p) << (p + 1);
                int n0 = high | low, n1 = n0 | (1 << p);
                float a0r = Ur[b * 16 + n0], a0i = Ui[b * 16 + n0];
                float a1r = Ur[b * 16 + n1], a1i = Ui[b * 16 + n1];
                float b0r, b0i, b1r, b1i;
                if (kind == 0) {        // RX
                    b0r = ch * a0r + sh * a1i;  b0i = ch * a0i - sh * a1r;
                    b1r = sh * a0i + ch * a1r;  b1i = -sh * a0r + ch * a1i;
                } else if (kind == 1) { // RY
                    b0r = ch * a0r - sh * a1r;  b0i = ch * a0i - sh * a1i;
                    b1r = sh * a0r + ch * a1r;  b1i = sh * a0i + ch * a1i;
                } else {                // RZ
                    b0r = ch * a0r + sh * a0i;  b0i = ch * a0i - sh * a0r;
                    b1r = ch * a1r - sh * a1i;  b1i = ch * a1i + sh * a1r;
                }
                Ur[b * 16 + n0] = b0r; Ui[b * 16 + n0] = b0i;
                Ur[b * 16 + n1] = b1r; Ui[b * 16 + n1] = b1i;
            }
        }
        __syncthreads();
    }
    // Stage 2: S[t][n] = sum_b sgn(b & zmask_t) * (Ur[b,n]Ur[b^x,n] + Ui[b,n]Ui[b^x,n])
    for (int item = tid; item < 81 * 16; item += blockDim.x) {
        const int t = item >> 4, n = item & 15;
        const int d3 = t % 3, d2 = (t / 3) % 3, d1 = (t / 9) % 3, d0 = t / 27;
        const int dd[4] = {d0, d1, d2, d3};
        int zmask = 0, xmask = 0;
        for (int k = 0; k < 4; ++k) {
            int p = 3 - k;
            if (dd[k] == 1) zmask |= 1 << p;
            else if (dd[k] == 2) xmask |= 1 << p;
        }
        float s = 0.f;
        for (int b2 = 0; b2 < 16; ++b2) {
            int bx = b2 ^ xmask;
            float sgn = (__popc(b2 & zmask) & 1) ? -1.f : 1.f;
            s += sgn * (Ur[b2 * 16 + n] * Ur[bx * 16 + n] +
                        Ui[b2 * 16 + n] * Ui[bx * 16 + n]);
        }
        S[item] = s;
    }
    __syncthreads();
    // Stage 3: g_W[j*81+t] = (1/16) sum_n z_j(n) * S[t][n]
    if (tid < 324) {
        const int j = tid / 81, t = tid % 81;
        float acc = 0.f;
        for (int n = 0; n < 16; ++n) {
            float zj = ((n >> (3 - j)) & 1) ? -1.f : 1.f;
            acc += zj * S[t * 16 + n];
        }
        g_W[tid] = acc * 0.0625f;
    }
}

// One thread per output pixel (i,j). Low register pressure: no mon[81];
// per-channel contraction acc_j += sum_a m01[a] * (sum_b W_j[a,b]*m23[b]).
// sin(pi x) via v_sin (input in revolutions): sin(2*pi*(x/2)).
__global__ void __launch_bounds__(256) quanv_kernel(const float* __restrict__ x,
                                                    float* __restrict__ out) {
    const int j = blockIdx.x * blockDim.x + threadIdx.x;
    const int i = blockIdx.y;
    if (j >= OUTHW) return;

    float acc0 = 0.f, acc1 = 0.f, acc2 = 0.f, acc3 = 0.f;

#pragma unroll
    for (int c = 0; c < 3; ++c) {
        const float* xc = x + (size_t)c * (IMGW * IMGW);
        const float p00 = xc[i * IMGW + j];
        const float p01 = xc[i * IMGW + j + 1];
        const float p10 = xc[(i + 1) * IMGW + j];
        const float p11 = xc[(i + 1) * IMGW + j + 1];
        // sin(pi p) = hw_sin(2*pi * (p/2)), cos(pi p) = hw_cos(2*pi * (p/2))
        const float c0 = __builtin_amdgcn_cosf(0.5f * p00), s0 = __builtin_amdgcn_sinf(0.5f * p00);
        const float c1 = __builtin_amdgcn_cosf(0.5f * p01), s1 = __builtin_amdgcn_sinf(0.5f * p01);
        const float c2 = __builtin_amdgcn_cosf(0.5f * p10), s2 = __builtin_amdgcn_sinf(0.5f * p10);
        const float c3 = __builtin_amdgcn_cosf(0.5f * p11), s3 = __builtin_amdgcn_sinf(0.5f * p11);
        const float v0[3] = {1.f, c0, s0};
        const float v1[3] = {1.f, c1, s1};
        const float v2[3] = {1.f, c2, s2};
        const float v3[3] = {1.f, c3, s3};
        float m01[9], m23[9];
#pragma unroll
        for (int a = 0; a < 3; ++a)
#pragma unroll
            for (int b = 0; b < 3; ++b) {
                m01[a * 3 + b] = v0[a] * v1[b];
                m23[a * 3 + b] = v2[a] * v3[b];
            }
        float t0 = 0.f, t1 = 0.f, t2 = 0.f, t3 = 0.f;
#pragma unroll
        for (int a = 0; a < 9; ++a) {
            float h0 = 0.f, h1 = 0.f, h2 = 0.f, h3 = 0.f;
#pragma unroll
            for (int b = 0; b < 9; ++b) {
                const float m = m23[b];
                h0 = fmaf(g_W[0 * 81 + a * 9 + b], m, h0);
                h1 = fmaf(g_W[1 * 81 + a * 9 + b], m, h1);
                h2 = fmaf(g_W[2 * 81 + a * 9 + b], m, h2);
                h3 = fmaf(g_W[3 * 81 + a * 9 + b], m, h3);
            }
            const float ma = m01[a];
            t0 = fmaf(ma, h0, t0);
            t1 = fmaf(ma, h1, t1);
            t2 = fmaf(ma, h2, t2);
            t3 = fmaf(ma, h3, t3);
        }
        acc0 += t0; acc1 += t1; acc2 += t2; acc3 += t3;
    }

    float4 o = make_float4(acc0, acc1, acc2, acc3);
    *reinterpret_cast<float4*>(out + (size_t)(i * OUTHW + j) * 4) = o;
}

extern "C" void kernel_launch(void* const* d_in, const int* in_sizes, int n_in,
                              void* d_out, int out_size, void* d_ws, size_t ws_size,
                              hipStream_t stream) {
    const float* x   = (const float*)d_in[0];   // [1,3,512,512] f32
    const float* wts = (const float*)d_in[1];   // [2,4] f32
    float* out = (float*)d_out;                 // [1,4,511,511] f32

    OpsPack ops = build_ops();  // deterministic host-side MT19937(42) replication

    hipLaunchKernelGGL(build_table, dim3(1), dim3(512), 0, stream, wts, ops);

    dim3 grid((OUTHW + 255) / 256, OUTHW);
    hipLaunchKernelGGL(quanv_kernel, grid, dim3(256), 0, stream, x, out);
}

// Round 3
// 25.518 us; speedup vs baseline: 1.5155x; 1.2668x over previous
//
#include <hip/hip_runtime.h>
#include <stdint.h>

#define NQ 4
#define OUTHW 511
#define IMGW 512
#define NOPS_MAX 64

struct OpsPack {
    int n;
    int kind[NOPS_MAX];   // 0=RX 1=RY 2=RZ 3=CNOT
    int wa[NOPS_MAX];     // wire (rot) or control (CNOT)
    int wb[NOPS_MAX];     // target (CNOT)
    int widx[NOPS_MAX];   // flat weight index l*4+i for rotations
};

// ---------- host-side MT19937, numpy RandomState-compatible ----------
namespace {
struct MT19937 {
    uint32_t mt[624]; int mti;
    explicit MT19937(uint32_t s) {
        mt[0] = s;
        for (int i = 1; i < 624; ++i)
            mt[i] = 1812433253u * (mt[i - 1] ^ (mt[i - 1] >> 30)) + (uint32_t)i;
        mti = 624;
    }
    uint32_t next32() {
        if (mti >= 624) {
            for (int i = 0; i < 624; ++i) {
                uint32_t y = (mt[i] & 0x80000000u) | (mt[(i + 1) % 624] & 0x7fffffffu);
                mt[i] = mt[(i + 397) % 624] ^ (y >> 1) ^ ((y & 1u) ? 0x9908b0dfu : 0u);
            }
            mti = 0;
        }
        uint32_t y = mt[mti++];
        y ^= y >> 11;
        y ^= (y << 7) & 0x9d2c5680u;
        y ^= (y << 15) & 0xefc60000u;
        y ^= y >> 18;
        return y;
    }
    double rand_double() {  // random_sample(): 2 draws
        uint32_t a = next32() >> 5, b = next32() >> 6;
        return (a * 67108864.0 + b) / 9007199254740992.0;
    }
    // numpy random_interval / legacy masked randint over [0, mx], 32-bit path
    uint32_t interval(uint32_t mx) {
        if (mx == 0) return 0;
        uint32_t mask = mx;
        mask |= mask >> 1; mask |= mask >> 2; mask |= mask >> 4;
        mask |= mask >> 8; mask |= mask >> 16;
        uint32_t v;
        while ((v = (next32() & mask)) > mx) {}
        return v;
    }
};

OpsPack build_ops() {
    MT19937 mt(42u);
    OpsPack P; P.n = 0;
    for (int l = 0; l < 2; ++l) {
        int i = 0;
        while (i < 4 && P.n < NOPS_MAX) {
            if (mt.rand_double() > 0.3) {
                int g = (int)mt.interval(2);  // randint(3)
                int w = (int)mt.interval(3);  // randint(4)
                P.kind[P.n] = g; P.wa[P.n] = w; P.wb[P.n] = 0; P.widx[P.n] = l * 4 + i;
                ++P.n; ++i;
            } else {
                // choice(4, size=2, replace=False) == permutation(4)[:2]
                int arr[4] = {0, 1, 2, 3};
                for (int ii = 3; ii >= 1; --ii) {
                    int j = (int)mt.interval((uint32_t)ii);
                    int t = arr[ii]; arr[ii] = arr[j]; arr[j] = t;
                }
                P.kind[P.n] = 3; P.wa[P.n] = arr[0]; P.wb[P.n] = arr[1]; P.widx[P.n] = -1;
                ++P.n;
            }
        }
    }
    return P;
}
}  // namespace

// 4 outputs x 81 monomial coefficients over {1, cos(pi x_k), sin(pi x_k)}^4
__device__ float g_W[4 * 81];

// One block of 256. Builds U (16x16) columns in LDS, then the coefficient table.
// HW trig: cos(th/2) = v_cos(th * 1/(4pi)) (input in revolutions), th in [0, 2pi).
__global__ void __launch_bounds__(256) build_table(const float* __restrict__ wts, OpsPack ops) {
    __shared__ float Ur[256];     // [b*16+n] = Re U[n][b]  (b = input basis col)
    __shared__ float Ui[256];
    __shared__ float S[81 * 16];  // partial sums over b, per (t, n)
    const int tid = threadIdx.x;
    Ur[tid] = ((tid >> 4) == (tid & 15)) ? 1.f : 0.f;
    Ui[tid] = 0.f;
    __syncthreads();
    const float INV4PI = 0.07957747154594767f;  // 1/(4*pi)
    for (int o = 0; o < ops.n; ++o) {
        const int kind = ops.kind[o];
        if (kind == 3) {  // CNOT(control=wa, target=wb)
            const int pc = 3 - ops.wa[o], pt = 3 - ops.wb[o];
            if (tid < 64) {
                int b = tid >> 2, q = tid & 3;
                int rem[2]; int ri = 0;
                for (int p = 0; p < 4; ++p) if (p != pc && p != pt) rem[ri++] = p;
                int n  = (1 << pc) | ((q & 1) ? (1 << rem[0]) : 0)
                                   | (((q >> 1) & 1) ? (1 << rem[1]) : 0);
                int n2 = n | (1 << pt);
                float tr = Ur[b * 16 + n]; Ur[b * 16 + n] = Ur[b * 16 + n2]; Ur[b * 16 + n2] = tr;
                float ti = Ui[b * 16 + n]; Ui[b * 16 + n] = Ui[b * 16 + n2]; Ui[b * 16 + n2] = ti;
            }
        } else {  // rotation on wire wa with angle wts[widx]
            const float th = wts[ops.widx[o]];
            const float ch = __builtin_amdgcn_cosf(th * INV4PI);
            const float sh = __builtin_amdgcn_sinf(th * INV4PI);
            const int p = 3 - ops.wa[o];
            if (tid < 128) {
                int b = tid >> 3, q = tid & 7;
                int low = q & ((1 << p) - 1);
                int high = (q >> p) << (p + 1);
                int n0 = high | low, n1 = n0 | (1 << p);
                float a0r = Ur[b * 16 + n0], a0i = Ui[b * 16 + n0];
                float a1r = Ur[b * 16 + n1], a1i = Ui[b * 16 + n1];
                float b0r, b0i, b1r, b1i;
                if (kind == 0) {        // RX
                    b0r = ch * a0r + sh * a1i;  b0i = ch * a0i - sh * a1r;
                    b1r = sh * a0i + ch * a1r;  b1i = -sh * a0r + ch * a1i;
                } else if (kind == 1) { // RY
                    b0r = ch * a0r - sh * a1r;  b0i = ch * a0i - sh * a1i;
                    b1r = sh * a0r + ch * a1r;  b1i = sh * a0i + ch * a1i;
                } else {                // RZ
                    b0r = ch * a0r + sh * a0i;  b0i = ch * a0i - sh * a0r;
                    b1r = ch * a1r - sh * a1i;  b1i = ch * a1i + sh * a1r;
                }
                Ur[b * 16 + n0] = b0r; Ui[b * 16 + n0] = b0i;
                Ur[b * 16 + n1] = b1r; Ui[b * 16 + n1] = b1i;
            }
        }
        __syncthreads();
    }
    // Stage 2: S[t][n] = sum_b sgn(b & zmask_t) * (Ur[b,n]Ur[b^x,n] + Ui[b,n]Ui[b^x,n])
    for (int item = tid; item < 81 * 16; item += 256) {
        const int t = item >> 4, n = item & 15;
        const int d3 = t % 3, d2 = (t / 3) % 3, d1 = (t / 9) % 3, d0 = t / 27;
        const int dd[4] = {d0, d1, d2, d3};
        int zmask = 0, xmask = 0;
        for (int k = 0; k < 4; ++k) {
            int p = 3 - k;
            if (dd[k] == 1) zmask |= 1 << p;
            else if (dd[k] == 2) xmask |= 1 << p;
        }
        float s = 0.f;
        for (int b2 = 0; b2 < 16; ++b2) {
            int bx = b2 ^ xmask;
            float sgn = (__popc(b2 & zmask) & 1) ? -1.f : 1.f;
            s += sgn * (Ur[b2 * 16 + n] * Ur[bx * 16 + n] +
                        Ui[b2 * 16 + n] * Ui[bx * 16 + n]);
        }
        S[item] = s;
    }
    __syncthreads();
    // Stage 3: g_W[j*81+t] = (1/16) sum_n z_j(n) * S[t][n]
    for (int item = tid; item < 324; item += 256) {
        const int j = item / 81, t = item % 81;
        float acc = 0.f;
        for (int n = 0; n < 16; ++n) {
            float zj = ((n >> (3 - j)) & 1) ? -1.f : 1.f;
            acc += zj * S[t * 16 + n];
        }
        g_W[item] = acc * 0.0625f;
    }
}

// One thread per output pixel (i,j). Monomial form: accumulate mon[81] over
// channels (81 FMA each, all compile-time indices -> registers), then ONE
// final contraction with g_W (uniform address -> scalar loads, read once).
__global__ void __launch_bounds__(256) quanv_kernel(const float* __restrict__ x,
                                                    float* __restrict__ out) {
    const int j = blockIdx.x * blockDim.x + threadIdx.x;
    const int i = blockIdx.y;
    if (j >= OUTHW) return;

    float mon[81];
#pragma unroll
    for (int t = 0; t < 81; ++t) mon[t] = 0.f;

#pragma unroll
    for (int c = 0; c < 3; ++c) {
        const float* xc = x + (size_t)c * (IMGW * IMGW);
        const float p00 = xc[i * IMGW + j];
        const float p01 = xc[i * IMGW + j + 1];
        const float p10 = xc[(i + 1) * IMGW + j];
        const float p11 = xc[(i + 1) * IMGW + j + 1];
        // sin(pi p) = v_sin(2pi * (p/2)): HW trig takes revolutions.
        const float c0 = __builtin_amdgcn_cosf(0.5f * p00), s0 = __builtin_amdgcn_sinf(0.5f * p00);
        const float c1 = __builtin_amdgcn_cosf(0.5f * p01), s1 = __builtin_amdgcn_sinf(0.5f * p01);
        const float c2 = __builtin_amdgcn_cosf(0.5f * p10), s2 = __builtin_amdgcn_sinf(0.5f * p10);
        const float c3 = __builtin_amdgcn_cosf(0.5f * p11), s3 = __builtin_amdgcn_sinf(0.5f * p11);
        const float v0[3] = {1.f, c0, s0};
        const float v1[3] = {1.f, c1, s1};
        const float v2[3] = {1.f, c2, s2};
        const float v3[3] = {1.f, c3, s3};
        float m01[9], m23[9];
#pragma unroll
        for (int a = 0; a < 3; ++a)
#pragma unroll
            for (int b = 0; b < 3; ++b) {
                m01[a * 3 + b] = v0[a] * v1[b];
                m23[a * 3 + b] = v2[a] * v3[b];
            }
#pragma unroll
        for (int a = 0; a < 9; ++a)
#pragma unroll
            for (int b = 0; b < 9; ++b)
                mon[a * 9 + b] = fmaf(m01[a], m23[b], mon[a * 9 + b]);
    }

    float acc0 = 0.f, acc1 = 0.f, acc2 = 0.f, acc3 = 0.f;
#pragma unroll
    for (int t = 0; t < 81; ++t) {
        const float m = mon[t];
        acc0 = fmaf(g_W[t], m, acc0);
        acc1 = fmaf(g_W[81 + t], m, acc1);
        acc2 = fmaf(g_W[162 + t], m, acc2);
        acc3 = fmaf(g_W[243 + t], m, acc3);
    }
    float4 o = make_float4(acc0, acc1, acc2, acc3);
    *reinterpret_cast<float4*>(out + (size_t)(i * OUTHW + j) * 4) = o;
}

extern "C" void kernel_launch(void* const* d_in, const int* in_sizes, int n_in,
                              void* d_out, int out_size, void* d_ws, size_t ws_size,
                              hipStream_t stream) {
    const float* x   = (const float*)d_in[0];   // [1,3,512,512] f32
    const float* wts = (const float*)d_in[1];   // [2,4] f32
    float* out = (float*)d_out;                 // [1,4,511,511] f32

    OpsPack ops = build_ops();  // deterministic host-side MT19937(42) replication

    hipLaunchKernelGGL(build_table, dim3(1), dim3(256), 0, stream, wts, ops);

    dim3 grid((OUTHW + 255) / 256, OUTHW);
    hipLaunchKernelGGL(quanv_kernel, grid, dim3(256), 0, stream, x, out);
}

// Round 4
// 12.801 us; speedup vs baseline: 3.0211x; 1.9934x over previous
//
#include <hip/hip_runtime.h>
#include <stdint.h>

#define OUTHW 511
#define IMGW 512

// ============ compile-time numpy RandomState(42) replication ============
struct COps { int n; int kind[64]; int wa[64]; int wb[64]; int widx[64]; };

struct CMT {
    uint32_t mt[624]; int mti;
    constexpr CMT(uint32_t s) : mt{}, mti(624) {
        mt[0] = s;
        for (int i = 1; i < 624; ++i)
            mt[i] = 1812433253u * (mt[i - 1] ^ (mt[i - 1] >> 30)) + (uint32_t)i;
    }
    constexpr uint32_t next32() {
        if (mti >= 624) {
            for (int i = 0; i < 624; ++i) {
                uint32_t y = (mt[i] & 0x80000000u) | (mt[(i + 1) % 624] & 0x7fffffffu);
                mt[i] = mt[(i + 397) % 624] ^ (y >> 1) ^ ((y & 1u) ? 0x9908b0dfu : 0u);
            }
            mti = 0;
        }
        uint32_t y = mt[mti++];
        y ^= y >> 11; y ^= (y << 7) & 0x9d2c5680u; y ^= (y << 15) & 0xefc60000u; y ^= y >> 18;
        return y;
    }
    constexpr double rand_double() {  // random_sample(): 2 draws
        uint32_t a = next32() >> 5, b = next32() >> 6;
        return (a * 67108864.0 + b) / 9007199254740992.0;
    }
    constexpr uint32_t interval(uint32_t mx) {  // legacy masked randint
        if (mx == 0) return 0;
        uint32_t mask = mx;
        mask |= mask >> 1; mask |= mask >> 2; mask |= mask >> 4;
        mask |= mask >> 8; mask |= mask >> 16;
        uint32_t v = next32() & mask;
        while (v > mx) v = next32() & mask;
        return v;
    }
};

constexpr COps build_ops_ce() {
    CMT mt(42u); COps P{}; P.n = 0;
    for (int l = 0; l < 2; ++l) {
        int i = 0;
        while (i < 4 && P.n < 64) {
            if (mt.rand_double() > 0.3) {
                int g = (int)mt.interval(2);  // randint(3)
                int w = (int)mt.interval(3);  // randint(4)
                P.kind[P.n] = g; P.wa[P.n] = w; P.wb[P.n] = 0; P.widx[P.n] = l * 4 + i;
                ++P.n; ++i;
            } else {  // choice(4,2,replace=False) == permutation(4)[:2]
                int arr[4] = {0, 1, 2, 3};
                for (int ii = 3; ii >= 1; --ii) {
                    int j = (int)mt.interval((uint32_t)ii);
                    int t = arr[ii]; arr[ii] = arr[j]; arr[j] = t;
                }
                P.kind[P.n] = 3; P.wa[P.n] = arr[0]; P.wb[P.n] = arr[1]; P.widx[P.n] = -1;
                ++P.n;
            }
        }
    }
    return P;
}
constexpr COps OPS = build_ops_ce();

// ===== compile-time Heisenberg support: which W_j[t] can be nonzero =====
// Symplectic Pauli code: bit k = x_k, bit 4+k = z_k. Propagate Z_j backward
// (reverse op order), splitting on anticommuting rotations (superset of true
// support -> skipping the complement is bit-exact).
struct Tabs {
    bool u[81];        // union support over j
    bool mj[4][81];    // per-output support
    int nu;            // |union|
    int tlist[81];     // compacted union t list
    int zm[81], xm[81];// stage-2 state-index masks per t
};

constexpr Tabs build_tabs() {
    Tabs T{};
    for (int j = 0; j < 4; ++j) {
        bool cur[256] = {};
        cur[1 << (4 + j)] = true;  // Z_j
        for (int o = OPS.n - 1; o >= 0; --o) {
            bool nxt[256] = {};
            for (int c = 0; c < 256; ++c) if (cur[c]) {
                if (OPS.kind[o] == 3) {  // CNOT: x_t ^= x_c ; z_c ^= z_t
                    int cc = OPS.wa[o], tt = OPS.wb[o], nc = c;
                    if (c & (1 << cc))       nc ^= (1 << tt);
                    if (c & (1 << (4 + tt))) nc ^= (1 << (4 + cc));
                    nxt[nc] = true;
                } else {
                    int w = OPS.wa[o];
                    int xw = (c >> w) & 1, zw = (c >> (4 + w)) & 1;
                    bool anti = false; int pm = 0;
                    if (OPS.kind[o] == 0)      { anti = zw != 0;        pm = 1 << w; }                 // RX
                    else if (OPS.kind[o] == 1) { anti = (xw ^ zw) != 0; pm = (1 << w) | (1 << (4 + w)); } // RY
                    else                       { anti = xw != 0;        pm = 1 << (4 + w); }            // RZ
                    nxt[c] = true;
                    if (anti) nxt[c ^ pm] = true;
                }
            }
            for (int c = 0; c < 256; ++c) cur[c] = nxt[c];
        }
        for (int c = 0; c < 256; ++c) if (cur[c]) {
            bool hasY = false; int t = 0;
            for (int k = 0; k < 4; ++k) {
                int xk = (c >> k) & 1, zk = (c >> (4 + k)) & 1;
                if (xk && zk) hasY = true;            // <Y> = 0 for real product state
                t = t * 3 + (zk ? 1 : (xk ? 2 : 0));  // qubit k at place 3^(3-k)
            }
            if (!hasY) { T.mj[j][t] = true; T.u[t] = true; }
        }
    }
    T.nu = 0;
    for (int t = 0; t < 81; ++t) {
        int dd[4] = {t / 27, (t / 9) % 3, (t / 3) % 3, t % 3};
        int zm = 0, xm = 0;
        for (int k = 0; k < 4; ++k) {
            int p = 3 - k;
            if (dd[k] == 1) zm |= 1 << p;
            else if (dd[k] == 2) xm |= 1 << p;
        }
        T.zm[t] = zm; T.xm[t] = xm;
        if (T.u[t]) T.tlist[T.nu++] = t;
    }
    return T;
}
constexpr Tabs TB = build_tabs();
constexpr int NU = TB.nu;

// 4 outputs x 81 monomial coefficients over {1, cos(pi x_k), sin(pi x_k)}^4
__device__ float g_W[4 * 81];

// One block of 512. Straight-line (compile-time ops) circuit sim + table.
__global__ void __launch_bounds__(512) build_table(const float* __restrict__ wts) {
    __shared__ float Ur[256];     // [b*16+n] = Re U[n][b]
    __shared__ float Ui[256];
    __shared__ float S[81 * 16];  // stage-2 partials per (t,n)
    const int tid = threadIdx.x;
    if (tid < 256) {
        Ur[tid] = ((tid >> 4) == (tid & 15)) ? 1.f : 0.f;
        Ui[tid] = 0.f;
    }
    __syncthreads();
    const float INV4PI = 0.07957747154594767f;  // 1/(4*pi)
#pragma unroll
    for (int o = 0; o < OPS.n; ++o) {
        if (OPS.kind[o] == 3) {  // CNOT — all wires compile-time constants
            const int pc = 3 - OPS.wa[o], pt = 3 - OPS.wb[o];
            if (tid < 64) {
                int b = tid >> 2, q = tid & 3;
                int rem[2]; int ri = 0;
#pragma unroll
                for (int p = 0; p < 4; ++p) if (p != pc && p != pt) rem[ri++] = p;
                int n  = (1 << pc) | ((q & 1) ? (1 << rem[0]) : 0)
                                   | (((q >> 1) & 1) ? (1 << rem[1]) : 0);
                int n2 = n | (1 << pt);
                float tr = Ur[b * 16 + n]; Ur[b * 16 + n] = Ur[b * 16 + n2]; Ur[b * 16 + n2] = tr;
                float ti = Ui[b * 16 + n]; Ui[b * 16 + n] = Ui[b * 16 + n2]; Ui[b * 16 + n2] = ti;
            }
        } else {  // rotation, kind/wire/weight-index compile-time
            const float th = wts[OPS.widx[o]];
            const float ch = __builtin_amdgcn_cosf(th * INV4PI);  // cos(th/2), rev units
            const float sh = __builtin_amdgcn_sinf(th * INV4PI);
            const int p = 3 - OPS.wa[o];
            if (tid < 128) {
                int b = tid >> 3, q = tid & 7;
                int low = q & ((1 << p) - 1);
                int high = (q >> p) << (p + 1);
                int n0 = high | low, n1 = n0 | (1 << p);
                float a0r = Ur[b * 16 + n0], a0i = Ui[b * 16 + n0];
                float a1r = Ur[b * 16 + n1], a1i = Ui[b * 16 + n1];
                float b0r, b0i, b1r, b1i;
                if (OPS.kind[o] == 0) {        // RX
                    b0r = ch * a0r + sh * a1i;  b0i = ch * a0i - sh * a1r;
                    b1r = sh * a0i + ch * a1r;  b1i = -sh * a0r + ch * a1i;
                } else if (OPS.kind[o] == 1) { // RY
                    b0r = ch * a0r - sh * a1r;  b0i = ch * a0i - sh * a1i;
                    b1r = sh * a0r + ch * a1r;  b1i = sh * a0i + ch * a1i;
                } else {                       // RZ
                    b0r = ch * a0r + sh * a0i;  b0i = ch * a0i - sh * a0r;
                    b1r = ch * a1r - sh * a1i;  b1i = ch * a1i + sh * a1r;
                }
                Ur[b * 16 + n0] = b0r; Ui[b * 16 + n0] = b0i;
                Ur[b * 16 + n1] = b1r; Ui[b * 16 + n1] = b1i;
            }
        }
        __syncthreads();
    }
    // Stage 2 (union-masked): S[t][n] = sum_b sgn(b&zm)(Ur[b,n]Ur[b^xm,n]+Ui...)
    for (int item = tid; item < NU * 16; item += 512) {
        const int t = TB.tlist[item >> 4], n = item & 15;
        const int zmask = TB.zm[t], xmask = TB.xm[t];
        float s = 0.f;
#pragma unroll
        for (int b2 = 0; b2 < 16; ++b2) {  // unrolled: 32 independent LDS reads
            int bx = b2 ^ xmask;
            float sgn = (__popc(b2 & zmask) & 1) ? -1.f : 1.f;
            s += sgn * (Ur[b2 * 16 + n] * Ur[bx * 16 + n] +
                        Ui[b2 * 16 + n] * Ui[bx * 16 + n]);
        }
        S[t * 16 + n] = s;
    }
    __syncthreads();
    // Stage 3: g_W[j*81+t] = (1/16) sum_n z_j(n) S[t][n], masked per (j,t)
    for (int item = tid; item < 324; item += 512) {
        const int j = item / 81, t = item % 81;
        if (!TB.mj[j][t]) continue;
        float acc = 0.f;
#pragma unroll
        for (int n = 0; n < 16; ++n) {
            float zj = ((n >> (3 - j)) & 1) ? -1.f : 1.f;
            acc += zj * S[t * 16 + n];
        }
        g_W[item] = acc * 0.0625f;
    }
}

// One thread per output pixel (i,j); support-masked monomial accumulation and
// contraction (masks are constexpr -> folded in the unrolled loops).
__global__ void __launch_bounds__(256) quanv_kernel(const float* __restrict__ x,
                                                    float* __restrict__ out) {
    const int j = blockIdx.x * blockDim.x + threadIdx.x;
    const int i = blockIdx.y;
    if (j >= OUTHW) return;

    float mon[81];
#pragma unroll
    for (int t = 0; t < 81; ++t) mon[t] = 0.f;

#pragma unroll
    for (int c = 0; c < 3; ++c) {
        const float* xc = x + (size_t)c * (IMGW * IMGW);
        const float p00 = xc[i * IMGW + j];
        const float p01 = xc[i * IMGW + j + 1];
        const float p10 = xc[(i + 1) * IMGW + j];
        const float p11 = xc[(i + 1) * IMGW + j + 1];
        // sin(pi p) = v_sin(2pi*(p/2)): HW trig takes revolutions
        const float c0 = __builtin_amdgcn_cosf(0.5f * p00), s0 = __builtin_amdgcn_sinf(0.5f * p00);
        const float c1 = __builtin_amdgcn_cosf(0.5f * p01), s1 = __builtin_amdgcn_sinf(0.5f * p01);
        const float c2 = __builtin_amdgcn_cosf(0.5f * p10), s2 = __builtin_amdgcn_sinf(0.5f * p10);
        const float c3 = __builtin_amdgcn_cosf(0.5f * p11), s3 = __builtin_amdgcn_sinf(0.5f * p11);
        const float v0[3] = {1.f, c0, s0};
        const float v1[3] = {1.f, c1, s1};
        const float v2[3] = {1.f, c2, s2};
        const float v3[3] = {1.f, c3, s3};
        float m01[9], m23[9];
#pragma unroll
        for (int a = 0; a < 3; ++a)
#pragma unroll
            for (int b = 0; b < 3; ++b) {
                m01[a * 3 + b] = v0[a] * v1[b];
                m23[a * 3 + b] = v2[a] * v3[b];
            }
#pragma unroll
        for (int a = 0; a < 9; ++a)
#pragma unroll
            for (int b = 0; b < 9; ++b)
                if (TB.u[a * 9 + b])  // constexpr-folded
                    mon[a * 9 + b] = fmaf(m01[a], m23[b], mon[a * 9 + b]);
    }

    float acc0 = 0.f, acc1 = 0.f, acc2 = 0.f, acc3 = 0.f;
#pragma unroll
    for (int t = 0; t < 81; ++t) {
        if (TB.mj[0][t]) acc0 = fmaf(g_W[0 * 81 + t], mon[t], acc0);
        if (TB.mj[1][t]) acc1 = fmaf(g_W[1 * 81 + t], mon[t], acc1);
        if (TB.mj[2][t]) acc2 = fmaf(g_W[2 * 81 + t], mon[t], acc2);
        if (TB.mj[3][t]) acc3 = fmaf(g_W[3 * 81 + t], mon[t], acc3);
    }
    float4 o = make_float4(acc0, acc1, acc2, acc3);
    *reinterpret_cast<float4*>(out + (size_t)(i * OUTHW + j) * 4) = o;
}

extern "C" void kernel_launch(void* const* d_in, const int* in_sizes, int n_in,
                              void* d_out, int out_size, void* d_ws, size_t ws_size,
                              hipStream_t stream) {
    const float* x   = (const float*)d_in[0];   // [1,3,512,512] f32
    const float* wts = (const float*)d_in[1];   // [2,4] f32
    float* out = (float*)d_out;                 // [1,4,511,511] f32

    hipLaunchKernelGGL(build_table, dim3(1), dim3(512), 0, stream, wts);

    dim3 grid((OUTHW + 255) / 256, OUTHW);
    hipLaunchKernelGGL(quanv_kernel, grid, dim3(256), 0, stream, x, out);
}